// Round 5
// baseline (3133.614 us; speedup 1.0000x reference)
//
#include <hip/hip_runtime.h>

#define B_ROWS 131072
#define NSTEP  65
#define ROWS   64                   // rows per block
#define NBLK   (B_ROWS / ROWS)      // 2048 blocks -> 3 blocks/CU resident

typedef __attribute__((ext_vector_type(8))) short short8;
typedef __attribute__((ext_vector_type(4))) float floatx4;
typedef __attribute__((ext_vector_type(4))) unsigned int uintx4;

__device__ __forceinline__ unsigned short f2bf(float f) {
    unsigned int u = __builtin_bit_cast(unsigned int, f);
    u += 0x7FFFu + ((u >> 16) & 1u);   // RNE; inputs are finite
    return (unsigned short)(u >> 16);
}
__device__ __forceinline__ float bf2f(unsigned short h) {
    unsigned int u = ((unsigned int)h) << 16;
    return __builtin_bit_cast(float, u);
}
// tile slot address for (row, col): 8-bf16 chunks XOR-swizzled by row&7
__device__ __forceinline__ int slotA(int row, int col) {
    return row * 64 + ((((col >> 3) ^ (row & 7)) << 3) | (col & 7));
}

// ---- pack W1 (65,63,256) fp32 -> bf16 frag order [stp][kc<2][n<256][32 k], k=63 zero-padded
__global__ __launch_bounds__(256) void pack_w1(const float* __restrict__ W1,
                                               unsigned short* __restrict__ out) {
    int t = blockIdx.x * 256 + threadIdx.x;            // 65*2*256 = 33280 threads
    int n = t & 255, kc = (t >> 8) & 1, stp = t >> 9;
    unsigned int wbuf[16];
#pragma unroll
    for (int e = 0; e < 16; ++e) {
        int k0 = kc * 32 + e * 2, k1 = k0 + 1;
        float v0 = (k0 < 63) ? W1[((size_t)stp * 63 + k0) * 256 + n] : 0.f;
        float v1 = (k1 < 63) ? W1[((size_t)stp * 63 + k1) * 256 + n] : 0.f;
        wbuf[e] = (unsigned)f2bf(v0) | ((unsigned)f2bf(v1) << 16);
    }
    uintx4* o = (uintx4*)out;
#pragma unroll
    for (int j = 0; j < 4; ++j) {
        uintx4 u = {wbuf[j*4+0], wbuf[j*4+1], wbuf[j*4+2], wbuf[j*4+3]};
        o[(size_t)t * 4 + j] = u;
    }
}

// ---- pack W2 (65,256,256) fp32 -> bf16 frag order [stp][kc<8][n<256][32 k]
__global__ __launch_bounds__(256) void pack_w2(const float* __restrict__ W2,
                                               unsigned short* __restrict__ out) {
    int t = blockIdx.x * 256 + threadIdx.x;            // 65*8*256 = 133120 threads
    int n = t & 255, kc = (t >> 8) & 7, stp = t >> 11;
    unsigned int wbuf[16];
#pragma unroll
    for (int e = 0; e < 16; ++e) {
        int k0 = kc * 32 + e * 2;
        float v0 = W2[((size_t)stp * 256 + k0) * 256 + n];
        float v1 = W2[((size_t)stp * 256 + k0 + 1) * 256 + n];
        wbuf[e] = (unsigned)f2bf(v0) | ((unsigned)f2bf(v1) << 16);
    }
    uintx4* o = (uintx4*)out;
#pragma unroll
    for (int j = 0; j < 4; ++j) {
        uintx4 u = {wbuf[j*4+0], wbuf[j*4+1], wbuf[j*4+2], wbuf[j*4+3]};
        o[(size_t)t * 4 + j] = u;
    }
}

// ---- whole 65-step flow; block owns 64 rows; bf16 tile IS the z master.
// z[row][i_next] is carried one step in a register (same lane saves/restores).
// Column 63 is read FRESH from the tile at every fixup (it changes at step 63,
// where i==63 and the same lane has just written the updated value -> RAW ok).
// Transposed-MFMA: A = weights (global frag-packed), B = activations (LDS).
// C-layout: lane holds col1 = i4*16+q*4+r, row = j*16+c.
__global__ __launch_bounds__(256, 3) void flow_kernel(
    const float* __restrict__ x,
    const float* __restrict__ sg,
    const unsigned short* __restrict__ Wb1p,
    const unsigned short* __restrict__ Wb2p,
    const float* __restrict__ b1g,
    const float* __restrict__ b2g,
    const float* __restrict__ w3g,
    const float* __restrict__ b3g,
    const int* __restrict__ idxg,
    float* __restrict__ out)
{
    __shared__ uintx4 tileA[ROWS * 8];   // bf16 z tile (master), swizzled      8,192 B
    __shared__ uintx4 H1[ROWS * 32];     // bf16 h1, swizzled                  32,768 B
    __shared__ float  TR[4][ROWS];       // per-wave partial t                  1,024 B

    const int tid  = threadIdx.x;
    const int w    = tid >> 6;           // wave 0..3 owns cols [w*64, w*64+64)
    const int lane = tid & 63;
    const int q    = lane >> 4;
    const int c    = lane & 15;
    const int b0   = blockIdx.x * ROWS;
    const int urow = w * 16 + c;         // row owned by this lane when q==0

    unsigned short*     tileS = (unsigned short*)tileA;
    unsigned long long* H1u   = (unsigned long long*)H1;
    const uintx4* w1v = (const uintx4*)Wb1p;
    const uintx4* w2v = (const uintx4*)Wb2p;

    // ---- init: coalesced x load -> tileA (bf16 master, swizzled)
#pragma unroll 4
    for (int it = 0; it < (ROWS * 64) / 256; ++it) {   // 16 iters
        int flat = it * 256 + tid;
        int row = flat >> 6, col = flat & 63;
        tileS[slotA(row, col)] = f2bf(x[(size_t)(b0 + row) * 64 + col]);
    }
    __syncthreads();

    // prologue: save z[urow][idx0], put (fresh) z[urow][63] into slot idx0
    float savedf = 0.f;
    {
        int i0 = idxg[0];
        if (q == 0) {
            savedf = bf2f(tileS[slotA(urow, i0)]);
            tileS[slotA(urow, i0)] = tileS[slotA(urow, 63)];
        }
    }
    __syncthreads();

#pragma unroll 1
    for (int step = 0; step < NSTEP; ++step) {
        const int i = idxg[step];

        floatx4 acc[4][4];
#pragma unroll
        for (int a = 0; a < 4; ++a)
#pragma unroll
            for (int b = 0; b < 4; ++b) acc[a][b] = (floatx4){0.f, 0.f, 0.f, 0.f};

        // ---- phase 1: h1^T = W1^T @ z^T   (K = 64)
#pragma unroll
        for (int kc = 0; kc < 2; ++kc) {
            short8 bz[4], aw[4];
#pragma unroll
            for (int j = 0; j < 4; ++j)
                bz[j] = __builtin_bit_cast(short8,
                    tileA[(j * 16 + c) * 8 + ((kc * 4 + q) ^ (c & 7))]);
#pragma unroll
            for (int i4 = 0; i4 < 4; ++i4)
                aw[i4] = __builtin_bit_cast(short8,
                    w1v[((size_t)(step * 2 + kc) * 256 + w * 64 + i4 * 16 + c) * 4 + q]);
#pragma unroll
            for (int i4 = 0; i4 < 4; ++i4)
#pragma unroll
                for (int j = 0; j < 4; ++j)
                    acc[i4][j] = __builtin_amdgcn_mfma_f32_16x16x32_bf16(
                        aw[i4], bz[j], acc[i4][j], 0, 0, 0);
        }

        // ---- epi-1: bias+relu -> H1 bf16 (4 consecutive cols per b64 store)
#pragma unroll
        for (int i4 = 0; i4 < 4; ++i4) {
            int cb = step * 256 + w * 64 + i4 * 16 + q * 4;
            float bb0 = b1g[cb + 0], bb1 = b1g[cb + 1], bb2 = b1g[cb + 2], bb3 = b1g[cb + 3];
            int c16 = (w * 8 + i4 * 2 + (q >> 1)) ^ c;   // swizzle mask = row&15 = c
#pragma unroll
            for (int j = 0; j < 4; ++j) {
                int row = j * 16 + c;
                float h0 = fmaxf(acc[i4][j][0] + bb0, 0.f);
                float h1 = fmaxf(acc[i4][j][1] + bb1, 0.f);
                float h2 = fmaxf(acc[i4][j][2] + bb2, 0.f);
                float h3 = fmaxf(acc[i4][j][3] + bb3, 0.f);
                unsigned d0 = (unsigned)f2bf(h0) | ((unsigned)f2bf(h1) << 16);
                unsigned d1 = (unsigned)f2bf(h2) | ((unsigned)f2bf(h3) << 16);
                H1u[(row * 32 + c16) * 2 + (q & 1)] =
                    (unsigned long long)d0 | ((unsigned long long)d1 << 32);
            }
        }
        __syncthreads();

        // ---- phase 2: h2^T = W2^T @ h1^T   (K = 256)
#pragma unroll
        for (int a = 0; a < 4; ++a)
#pragma unroll
            for (int b = 0; b < 4; ++b) acc[a][b] = (floatx4){0.f, 0.f, 0.f, 0.f};

#pragma unroll
        for (int kc = 0; kc < 8; ++kc) {
            short8 bh[4], aw[4];
#pragma unroll
            for (int j = 0; j < 4; ++j)
                bh[j] = __builtin_bit_cast(short8,
                    H1[(j * 16 + c) * 32 + ((kc * 4 + q) ^ c)]);
#pragma unroll
            for (int i4 = 0; i4 < 4; ++i4)
                aw[i4] = __builtin_bit_cast(short8,
                    w2v[((size_t)(step * 8 + kc) * 256 + w * 64 + i4 * 16 + c) * 4 + q]);
#pragma unroll
            for (int i4 = 0; i4 < 4; ++i4)
#pragma unroll
                for (int j = 0; j < 4; ++j)
                    acc[i4][j] = __builtin_amdgcn_mfma_f32_16x16x32_bf16(
                        aw[i4], bh[j], acc[i4][j], 0, 0, 0);
        }

        // ---- epi-2: t = relu(h2 + b2) . w3 (16 cols in-register; 2 shuffles)
        {
            float p[4];
#pragma unroll
            for (int j = 0; j < 4; ++j) p[j] = 0.f;
#pragma unroll
            for (int i4 = 0; i4 < 4; ++i4) {
#pragma unroll
                for (int r = 0; r < 4; ++r) {
                    int col2 = step * 256 + w * 64 + i4 * 16 + q * 4 + r;
                    float bb = b2g[col2];
                    float ww = w3g[col2];
#pragma unroll
                    for (int j = 0; j < 4; ++j)
                        p[j] += fmaxf(acc[i4][j][r] + bb, 0.f) * ww;
                }
            }
#pragma unroll
            for (int j = 0; j < 4; ++j) {
                float t = p[j];
                t += __shfl_xor(t, 16, 64);
                t += __shfl_xor(t, 32, 64);
                if (q == 0) TR[w][j * 16 + c] = t;
            }
        }
        __syncthreads();

        // ---- update (16 lanes/wave): z[urow][i] = saved + t; then save
        //      z[urow][i_next] and overwrite its slot with FRESH z[urow][63]
        if (q == 0) {
            float t = TR[0][urow] + TR[1][urow] + TR[2][urow] + TR[3][urow] + b3g[step];
            float nz = savedf + t;
            tileS[slotA(urow, i)] = f2bf(nz);
            if (step + 1 < NSTEP) {
                int in = idxg[step + 1];
                savedf = bf2f(tileS[slotA(urow, in)]);
                // fresh col63: at step 63 (i==63) the store above just updated it
                tileS[slotA(urow, in)] = tileS[slotA(urow, 63)];
            }
        }
        __syncthreads();
    }

    // ---- finalize: out[b][j] = exp(s[j]) * z  (z read from bf16 tile)
    float* sExp = (float*)TR;
    if (tid < 64) sExp[tid] = expf(sg[tid]);
    __syncthreads();
#pragma unroll 4
    for (int it = 0; it < (ROWS * 64) / 256; ++it) {
        int flat = it * 256 + tid;
        int row = flat >> 6, col = flat & 63;
        out[(size_t)(b0 + row) * 64 + col] = sExp[col] * bf2f(tileS[slotA(row, col)]);
    }
}

extern "C" void kernel_launch(void* const* d_in, const int* in_sizes, int n_in,
                              void* d_out, int out_size, void* d_ws, size_t ws_size,
                              hipStream_t stream) {
    const float* x  = (const float*)d_in[0];
    const float* s  = (const float*)d_in[1];
    const float* W1 = (const float*)d_in[2];
    const float* b1 = (const float*)d_in[3];
    const float* W2 = (const float*)d_in[4];
    const float* b2 = (const float*)d_in[5];
    const float* W3 = (const float*)d_in[6];
    const float* b3 = (const float*)d_in[7];
    const int* idx  = (const int*)d_in[8];
    float* out = (float*)d_out;

    char* ws = (char*)d_ws;
    const size_t W1P_BYTES = (size_t)NSTEP * 2 * 256 * 32 * 2;   //  2,129,920
    unsigned short* Wb1p = (unsigned short*)ws;
    unsigned short* Wb2p = (unsigned short*)(ws + W1P_BYTES);

    pack_w1<<<130, 256, 0, stream>>>(W1, Wb1p);
    pack_w2<<<520, 256, 0, stream>>>(W2, Wb2p);
    flow_kernel<<<NBLK, 256, 0, stream>>>(x, s, Wb1p, Wb2p, b1, b2, W3, b3, idx, out);
}